// Round 5
// baseline (817.379 us; speedup 1.0000x reference)
//
#include <hip/hip_runtime.h>
#include <math.h>

#define HDIM 4096
#define VDIM 32000
#define GBLK (HDIM / 4)    // 1024 gate blocks, 4 rows each
#define LBLK (VDIM / 16)   // 2000 logit blocks, 16 rows each

typedef float floatx4 __attribute__((ext_vector_type(4)));

union F2U { float2 f2; unsigned long long u; };

__device__ inline float wave_reduce_sum(float v) {
    #pragma unroll
    for (int off = 32; off > 0; off >>= 1)
        v += __shfl_down(v, off, 64);
    return v;
}

__device__ inline floatx4 ntload4(const float* p) {
    return __builtin_nontemporal_load(reinterpret_cast<const floatx4*>(p));
}

__device__ inline float dot4(floatx4 a, floatx4 b) {
    return a.x * b.x + a.y * b.y + a.z * b.z + a.w * b.w;
}

// 1024 blocks x 256 threads. Block b owns rows [4b, 4b+4). Wave g computes
// gate g for all 4 rows (8 independent weight streams -> deep MLP).
// Block 0 also resets the sync vars used by the following kernel (this kernel
// fully completes before the logits kernel starts -> visible, race-free).
__global__ __launch_bounds__(256) void lstm_gates_kernel(
    const float* __restrict__ prev_h, const float* __restrict__ prev_c,
    const float* __restrict__ x_t,
    const float* __restrict__ w_xf, const float* __restrict__ w_hf, const float* __restrict__ b_f,
    const float* __restrict__ w_xi, const float* __restrict__ w_hi, const float* __restrict__ b_i,
    const float* __restrict__ w_xg, const float* __restrict__ w_hg, const float* __restrict__ b_g,
    const float* __restrict__ w_xo, const float* __restrict__ w_ho, const float* __restrict__ b_o,
    float* __restrict__ out, int* __restrict__ sync)
{
    if (blockIdx.x == 0 && threadIdx.x == 0) { sync[0] = 0; sync[1] = 0; }

    __shared__ float s_x[HDIM];
    __shared__ float s_h[HDIM];
    __shared__ float sg[4][4];   // [gate][row]
    for (int i = threadIdx.x * 4; i < HDIM; i += 256 * 4) {
        *reinterpret_cast<float4*>(&s_x[i]) = *reinterpret_cast<const float4*>(&x_t[i]);
        *reinterpret_cast<float4*>(&s_h[i]) = *reinterpret_cast<const float4*>(&prev_h[i]);
    }
    __syncthreads();

    const int wave = threadIdx.x >> 6;
    const int lane = threadIdx.x & 63;
    const int row0 = blockIdx.x * 4;

    const float* wx; const float* wh; const float* bb;
    if      (wave == 0) { wx = w_xf; wh = w_hf; bb = b_f; }
    else if (wave == 1) { wx = w_xi; wh = w_hi; bb = b_i; }
    else if (wave == 2) { wx = w_xg; wh = w_hg; bb = b_g; }
    else                { wx = w_xo; wh = w_ho; bb = b_o; }
    wx += (size_t)row0 * HDIM;
    wh += (size_t)row0 * HDIM;

    float acc[4] = {0.f, 0.f, 0.f, 0.f};
    for (int j = lane * 4; j < HDIM; j += 64 * 4) {
        floatx4 v = *reinterpret_cast<const floatx4*>(&s_x[j]);
        floatx4 u = *reinterpret_cast<const floatx4*>(&s_h[j]);
        #pragma unroll
        for (int r = 0; r < 4; ++r) {
            floatx4 a = ntload4(wx + (size_t)r * HDIM + j);
            floatx4 b = ntload4(wh + (size_t)r * HDIM + j);
            acc[r] += dot4(a, v) + dot4(b, u);
        }
    }
    #pragma unroll
    for (int r = 0; r < 4; ++r) {
        float s = wave_reduce_sum(acc[r]);
        if (lane == 0) sg[wave][r] = s + bb[row0 + r];
    }
    __syncthreads();

    if (threadIdx.x < 4) {
        const int r   = threadIdx.x;
        const int row = row0 + r;
        float ft = 1.f / (1.f + expf(-sg[0][r]));
        float it = 1.f / (1.f + expf(-sg[1][r]));
        float gt = tanhf(sg[2][r]);
        float ot = 1.f / (1.f + expf(-sg[3][r]));
        float c  = ft * prev_c[row] + it * gt;
        float h  = ot * tanhf(c);
        out[row]        = h;   // h_t
        out[HDIM + row] = c;   // c_t
    }
}

// 2000 blocks x 256 threads. Block b owns rows [16b, 16b+16); wave w computes
// rows 16b+4w .. +3 with 4 weight streams. Softmax is finished in-kernel via
// the last-block pattern: partials -> device-scope counter -> last block
// combines and publishes (M, 1/S) -> everyone normalizes their own 16 logits
// held in LDS (logits never round-trip through global memory).
__global__ __launch_bounds__(256) void logits_softmax_kernel(
    const float* __restrict__ w_hy, const float* __restrict__ b_y,
    const float* __restrict__ h, float2* __restrict__ part,
    float* __restrict__ stats, int* __restrict__ sync,
    float* __restrict__ y)
{
    __shared__ float s_h[HDIM];
    __shared__ float sl[16];
    __shared__ float s_MR[2];
    __shared__ float wm[4], wsum[4];
    __shared__ int   s_role;

    for (int i = threadIdx.x * 4; i < HDIM; i += 256 * 4)
        *reinterpret_cast<float4*>(&s_h[i]) = *reinterpret_cast<const float4*>(&h[i]);
    __syncthreads();

    const int wave = threadIdx.x >> 6;
    const int lane = threadIdx.x & 63;
    const int row0 = blockIdx.x * 16 + wave * 4;
    const float* w = w_hy + (size_t)row0 * HDIM;

    float acc[4] = {0.f, 0.f, 0.f, 0.f};
    for (int j = lane * 4; j < HDIM; j += 64 * 4) {
        floatx4 u = *reinterpret_cast<const floatx4*>(&s_h[j]);
        #pragma unroll
        for (int r = 0; r < 4; ++r) {
            floatx4 a = ntload4(w + (size_t)r * HDIM + j);
            acc[r] += dot4(a, u);
        }
    }
    #pragma unroll
    for (int r = 0; r < 4; ++r) {
        float s = wave_reduce_sum(acc[r]);
        if (lane == 0) sl[wave * 4 + r] = s + b_y[row0 + r];
    }
    __syncthreads();

    // publish this block's (max, sum-exp) partial; count arrivals
    if (threadIdx.x == 0) {
        float m = sl[0];
        #pragma unroll
        for (int i = 1; i < 16; ++i) m = fmaxf(m, sl[i]);
        float e = 0.f;
        #pragma unroll
        for (int i = 0; i < 16; ++i) e += expf(sl[i] - m);
        F2U pu; pu.f2 = make_float2(m, e);
        __hip_atomic_store(reinterpret_cast<unsigned long long*>(&part[blockIdx.x]), pu.u,
                           __ATOMIC_RELEASE, __HIP_MEMORY_SCOPE_AGENT);
        int old = __hip_atomic_fetch_add(&sync[0], 1, __ATOMIC_ACQ_REL, __HIP_MEMORY_SCOPE_AGENT);
        s_role = (old == LBLK - 1) ? 1 : 0;
    }
    __syncthreads();

    if (s_role) {
        // last block: combine all LBLK partials (online merge), publish stats
        float m = -1e30f, s = 0.f;
        for (int i = threadIdx.x; i < LBLK; i += 256) {
            F2U pu;
            pu.u = __hip_atomic_load(reinterpret_cast<unsigned long long*>(&part[i]),
                                     __ATOMIC_RELAXED, __HIP_MEMORY_SCOPE_AGENT);
            float pm = pu.f2.x, ps = pu.f2.y;
            if (pm > m) { s = s * expf(m - pm) + ps; m = pm; }
            else        { s += ps * expf(pm - m); }
        }
        #pragma unroll
        for (int off = 32; off > 0; off >>= 1) {
            float om = __shfl_xor(m, off, 64);
            float os = __shfl_xor(s, off, 64);
            float M2 = fmaxf(m, om);
            s = s * expf(m - M2) + os * expf(om - M2);
            m = M2;
        }
        if (lane == 0) { wm[wave] = m; wsum[wave] = s; }
        __syncthreads();
        if (threadIdx.x == 0) {
            float M = wm[0];
            #pragma unroll
            for (int i = 1; i < 4; ++i) M = fmaxf(M, wm[i]);
            float S = 0.f;
            #pragma unroll
            for (int i = 0; i < 4; ++i) S += wsum[i] * expf(wm[i] - M);
            float R = 1.f / S;
            s_MR[0] = M; s_MR[1] = R;
            __hip_atomic_store(&stats[0], M, __ATOMIC_RELAXED, __HIP_MEMORY_SCOPE_AGENT);
            __hip_atomic_store(&stats[1], R, __ATOMIC_RELEASE, __HIP_MEMORY_SCOPE_AGENT);
            __hip_atomic_store(&sync[1], 1, __ATOMIC_RELEASE, __HIP_MEMORY_SCOPE_AGENT);
        }
        __syncthreads();
    } else {
        if (threadIdx.x == 0) {
            while (__hip_atomic_load(&sync[1], __ATOMIC_ACQUIRE, __HIP_MEMORY_SCOPE_AGENT) == 0)
                __builtin_amdgcn_s_sleep(8);
            s_MR[0] = __hip_atomic_load(&stats[0], __ATOMIC_RELAXED, __HIP_MEMORY_SCOPE_AGENT);
            s_MR[1] = __hip_atomic_load(&stats[1], __ATOMIC_RELAXED, __HIP_MEMORY_SCOPE_AGENT);
        }
        __syncthreads();
    }

    if (threadIdx.x < 16)
        y[blockIdx.x * 16 + threadIdx.x] = expf(sl[threadIdx.x] - s_MR[0]) * s_MR[1];
}

extern "C" void kernel_launch(void* const* d_in, const int* in_sizes, int n_in,
                              void* d_out, int out_size, void* d_ws, size_t ws_size,
                              hipStream_t stream)
{
    const float* prev_h = (const float*)d_in[0];
    const float* prev_c = (const float*)d_in[1];
    const float* x_t    = (const float*)d_in[2];
    const float* w_xf   = (const float*)d_in[3];
    const float* w_hf   = (const float*)d_in[4];
    const float* b_f    = (const float*)d_in[5];
    const float* w_xi   = (const float*)d_in[6];
    const float* w_hi   = (const float*)d_in[7];
    const float* b_i    = (const float*)d_in[8];
    const float* w_xg   = (const float*)d_in[9];
    const float* w_hg   = (const float*)d_in[10];
    const float* b_g    = (const float*)d_in[11];
    const float* w_xo   = (const float*)d_in[12];
    const float* w_ho   = (const float*)d_in[13];
    const float* b_o    = (const float*)d_in[14];
    const float* w_hy   = (const float*)d_in[15];
    const float* b_y    = (const float*)d_in[16];

    float* out = (float*)d_out;
    float* h_t = out;              // [0, H)
    float* y_t = out + 2 * HDIM;   // [2H, 2H+V)

    float2* part  = (float2*)d_ws;              // LBLK float2 (16 KB)
    float*  stats = (float*)(part + LBLK);      // 2 floats
    int*    sync  = (int*)(stats + 2);          // counter, flag

    lstm_gates_kernel<<<GBLK, 256, 0, stream>>>(
        prev_h, prev_c, x_t,
        w_xf, w_hf, b_f, w_xi, w_hi, b_i,
        w_xg, w_hg, b_g, w_xo, w_ho, b_o, out, sync);

    logits_softmax_kernel<<<LBLK, 256, 0, stream>>>(
        w_hy, b_y, h_t, part, stats, sync, y_t);
}

// Round 6
// 188.141 us; speedup vs baseline: 4.3445x; 4.3445x over previous
//
#include <hip/hip_runtime.h>
#include <math.h>

#define HDIM 4096
#define VDIM 32000
#define GBLK (HDIM / 4)    // 1024 gate blocks, 4 rows each
#define LBLK (VDIM / 16)   // 2000 logit blocks, 16 rows each
#define NBLK 125           // norm blocks: 125 * 256 = 32000 threads, 1 logit each

typedef float floatx4 __attribute__((ext_vector_type(4)));

__device__ inline float wave_reduce_sum(float v) {
    #pragma unroll
    for (int off = 32; off > 0; off >>= 1)
        v += __shfl_down(v, off, 64);
    return v;
}

__device__ inline floatx4 ntload4(const float* p) {
    return __builtin_nontemporal_load(reinterpret_cast<const floatx4*>(p));
}

__device__ inline float dot4(floatx4 a, floatx4 b) {
    return a.x * b.x + a.y * b.y + a.z * b.z + a.w * b.w;
}

// 1024 blocks x 256 threads. Block b owns rows [4b, 4b+4). Wave g computes
// gate g for all 4 rows (8 independent weight streams -> deep MLP).
__global__ __launch_bounds__(256) void lstm_gates_kernel(
    const float* __restrict__ prev_h, const float* __restrict__ prev_c,
    const float* __restrict__ x_t,
    const float* __restrict__ w_xf, const float* __restrict__ w_hf, const float* __restrict__ b_f,
    const float* __restrict__ w_xi, const float* __restrict__ w_hi, const float* __restrict__ b_i,
    const float* __restrict__ w_xg, const float* __restrict__ w_hg, const float* __restrict__ b_g,
    const float* __restrict__ w_xo, const float* __restrict__ w_ho, const float* __restrict__ b_o,
    float* __restrict__ out)
{
    __shared__ float s_x[HDIM];
    __shared__ float s_h[HDIM];
    __shared__ float sg[4][4];   // [gate][row]
    for (int i = threadIdx.x * 4; i < HDIM; i += 256 * 4) {
        *reinterpret_cast<float4*>(&s_x[i]) = *reinterpret_cast<const float4*>(&x_t[i]);
        *reinterpret_cast<float4*>(&s_h[i]) = *reinterpret_cast<const float4*>(&prev_h[i]);
    }
    __syncthreads();

    const int wave = threadIdx.x >> 6;
    const int lane = threadIdx.x & 63;
    const int row0 = blockIdx.x * 4;

    const float* wx; const float* wh; const float* bb;
    if      (wave == 0) { wx = w_xf; wh = w_hf; bb = b_f; }
    else if (wave == 1) { wx = w_xi; wh = w_hi; bb = b_i; }
    else if (wave == 2) { wx = w_xg; wh = w_hg; bb = b_g; }
    else                { wx = w_xo; wh = w_ho; bb = b_o; }
    wx += (size_t)row0 * HDIM;
    wh += (size_t)row0 * HDIM;

    float acc[4] = {0.f, 0.f, 0.f, 0.f};
    for (int j = lane * 4; j < HDIM; j += 64 * 4) {
        floatx4 v = *reinterpret_cast<const floatx4*>(&s_x[j]);
        floatx4 u = *reinterpret_cast<const floatx4*>(&s_h[j]);
        #pragma unroll
        for (int r = 0; r < 4; ++r) {
            floatx4 a = ntload4(wx + (size_t)r * HDIM + j);
            floatx4 b = ntload4(wh + (size_t)r * HDIM + j);
            acc[r] += dot4(a, v) + dot4(b, u);
        }
    }
    #pragma unroll
    for (int r = 0; r < 4; ++r) {
        float s = wave_reduce_sum(acc[r]);
        if (lane == 0) sg[wave][r] = s + bb[row0 + r];
    }
    __syncthreads();

    if (threadIdx.x < 4) {
        const int r   = threadIdx.x;
        const int row = row0 + r;
        float ft = 1.f / (1.f + expf(-sg[0][r]));
        float it = 1.f / (1.f + expf(-sg[1][r]));
        float gt = tanhf(sg[2][r]);
        float ot = 1.f / (1.f + expf(-sg[3][r]));
        float c  = ft * prev_c[row] + it * gt;
        float h  = ot * tanhf(c);
        out[row]        = h;   // h_t
        out[HDIM + row] = c;   // c_t
    }
}

// 2000 blocks x 256 threads. Block b owns rows [16b, 16b+16); wave w computes
// rows 16b+4w .. +3 with 4 weight streams. Block also emits its (m, sum-exp)
// softmax partial via plain stores (visibility via kernel boundary).
__global__ __launch_bounds__(256) void logits_kernel(
    const float* __restrict__ w_hy, const float* __restrict__ b_y,
    const float* __restrict__ h, float* __restrict__ logits,
    float2* __restrict__ part)
{
    __shared__ float s_h[HDIM];
    __shared__ float sl[16];
    for (int i = threadIdx.x * 4; i < HDIM; i += 256 * 4)
        *reinterpret_cast<float4*>(&s_h[i]) = *reinterpret_cast<const float4*>(&h[i]);
    __syncthreads();

    const int wave = threadIdx.x >> 6;
    const int lane = threadIdx.x & 63;
    const int row0 = blockIdx.x * 16 + wave * 4;
    const float* w = w_hy + (size_t)row0 * HDIM;

    float acc[4] = {0.f, 0.f, 0.f, 0.f};
    for (int j = lane * 4; j < HDIM; j += 64 * 4) {
        floatx4 u = *reinterpret_cast<const floatx4*>(&s_h[j]);
        #pragma unroll
        for (int r = 0; r < 4; ++r) {
            floatx4 a = ntload4(w + (size_t)r * HDIM + j);
            acc[r] += dot4(a, u);
        }
    }
    #pragma unroll
    for (int r = 0; r < 4; ++r) {
        float s = wave_reduce_sum(acc[r]);
        if (lane == 0) {
            float lv = s + b_y[row0 + r];
            logits[row0 + r] = lv;
            sl[wave * 4 + r] = lv;
        }
    }
    __syncthreads();

    if (threadIdx.x < 16) {
        float v = sl[threadIdx.x];
        float m = v;
        #pragma unroll
        for (int off = 8; off > 0; off >>= 1)
            m = fmaxf(m, __shfl_xor(m, off, 64));
        float e = expf(v - m);
        #pragma unroll
        for (int off = 8; off > 0; off >>= 1)
            e += __shfl_xor(e, off, 64);
        if (threadIdx.x == 0) part[blockIdx.x] = make_float2(m, e);
    }
}

// 125 blocks x 256 threads. Each block redundantly combines the 2000 partials
// (16 KB, L2-hot) to get (M, 1/S), then normalizes its own 256 logits.
__global__ __launch_bounds__(256) void softmax_norm_kernel(
    const float* __restrict__ logits, const float2* __restrict__ part,
    float* __restrict__ y)
{
    const int tid  = threadIdx.x;
    const int wave = tid >> 6;
    const int lane = tid & 63;

    // online merge of 8 partials per thread
    float m = -1e30f, s = 0.f;
    for (int i = tid; i < LBLK; i += 256) {
        float2 p = part[i];
        if (p.x > m) { s = s * expf(m - p.x) + p.y; m = p.x; }
        else         { s += p.y * expf(p.x - m); }
    }
    // wave-level merge
    #pragma unroll
    for (int off = 32; off > 0; off >>= 1) {
        float om = __shfl_xor(m, off, 64);
        float os = __shfl_xor(s, off, 64);
        float M2 = fmaxf(m, om);
        s = s * expf(m - M2) + os * expf(om - M2);
        m = M2;
    }
    __shared__ float wm[4], ws[4];
    if (lane == 0) { wm[wave] = m; ws[wave] = s; }
    __syncthreads();
    float M = fmaxf(fmaxf(wm[0], wm[1]), fmaxf(wm[2], wm[3]));
    float S = ws[0] * expf(wm[0] - M) + ws[1] * expf(wm[1] - M)
            + ws[2] * expf(wm[2] - M) + ws[3] * expf(wm[3] - M);
    float R = 1.f / S;

    const int idx = blockIdx.x * 256 + tid;
    y[idx] = expf(logits[idx] - M) * R;
}

extern "C" void kernel_launch(void* const* d_in, const int* in_sizes, int n_in,
                              void* d_out, int out_size, void* d_ws, size_t ws_size,
                              hipStream_t stream)
{
    const float* prev_h = (const float*)d_in[0];
    const float* prev_c = (const float*)d_in[1];
    const float* x_t    = (const float*)d_in[2];
    const float* w_xf   = (const float*)d_in[3];
    const float* w_hf   = (const float*)d_in[4];
    const float* b_f    = (const float*)d_in[5];
    const float* w_xi   = (const float*)d_in[6];
    const float* w_hi   = (const float*)d_in[7];
    const float* b_i    = (const float*)d_in[8];
    const float* w_xg   = (const float*)d_in[9];
    const float* w_hg   = (const float*)d_in[10];
    const float* b_g    = (const float*)d_in[11];
    const float* w_xo   = (const float*)d_in[12];
    const float* w_ho   = (const float*)d_in[13];
    const float* b_o    = (const float*)d_in[14];
    const float* w_hy   = (const float*)d_in[15];
    const float* b_y    = (const float*)d_in[16];

    float* out = (float*)d_out;
    float* h_t = out;              // [0, H)
    float* y_t = out + 2 * HDIM;   // [2H, 2H+V)

    float*  logits = (float*)d_ws;            // V floats
    float2* part   = (float2*)(logits + VDIM);// LBLK float2

    lstm_gates_kernel<<<GBLK, 256, 0, stream>>>(
        prev_h, prev_c, x_t,
        w_xf, w_hf, b_f, w_xi, w_hi, b_i,
        w_xg, w_hg, b_g, w_xo, w_ho, b_o, out);

    logits_kernel<<<LBLK, 256, 0, stream>>>(w_hy, b_y, h_t, logits, part);

    softmax_norm_kernel<<<NBLK, 256, 0, stream>>>(logits, part, y_t);
}